// Round 1
// baseline (3309.663 us; speedup 1.0000x reference)
//
#include <hip/hip_runtime.h>
#include <math.h>

#define B_      256
#define CHANS   22
#define SAMPLES 1125
#define DEPTH   9
#define CD1     24
#define CD2     9
#define KT      75
#define W1      1051
#define WP      210
#define FEAT    1890
#define TW      16
#define NT      66   // ceil(1051/16)

// workspace float offsets
#define WS_W2   0      // 24*22  folded stage1/2/bn1/bn2 weight
#define WS_D    528    // 24     folded bias
#define WS_CC1  552    // 9*24   a3*22*cconv1_w
#define WS_B3   768    // 9
#define WS_L1   777    // 484    T1 = -D^-1/2 A D^-1/2
#define WS_L2   1261   // 484    T2 = 2*T1^2 - I
#define WS_CC2  1745   // 9*22   a4*cconv2_w
#define WS_B4   1943   // 9
#define WS_BL   1952   // 5*9    summed cheby bias per layer
#define WS_Z    2048   // 256*9*1051 z-buffer

__device__ __forceinline__ float gelu_exact(float v) {
    return 0.5f * v * (1.0f + erff(v * 0.70710678118654752f));
}

__global__ __launch_bounds__(256) void precompute_kernel(
    const float* __restrict__ cw, const float* __restrict__ t1w,
    const float* __restrict__ bn1, const float* __restrict__ t2w,
    const float* __restrict__ bn2, const float* __restrict__ cc1w,
    const float* __restrict__ bn3, const float* __restrict__ A,
    const float* __restrict__ Am, const float* __restrict__ cbB,
    const float* __restrict__ cc2w, const float* __restrict__ bn4,
    float* __restrict__ ws)
{
    __shared__ float a1[CD1], a2[CD1];
    __shared__ float a3[CD2], a4[CD2];
    __shared__ float Ap[484], As[484], dis[22], L1s[484];
    const int tid = threadIdx.x;

    if (tid < CD1) {
        float g1 = bn1[tid], be1 = bn1[24 + tid], m1 = bn1[48 + tid], v1 = bn1[72 + tid];
        a1[tid] = g1 * rsqrtf(v1 + 1e-5f);
        float b1v = be1 - m1 * a1[tid];
        float g2 = bn2[tid], be2 = bn2[24 + tid], m2 = bn2[48 + tid], v2 = bn2[72 + tid];
        a2[tid] = g2 * rsqrtf(v2 + 1e-5f);
        float b2v = be2 - m2 * a2[tid];
        float S = 0.0f;
        for (int k = 0; k < KT; ++k) S += t2w[tid * KT + k];
        ws[WS_D + tid] = a2[tid] * b1v * S + b2v;
    }
    if (tid < CD2) {
        float g3 = bn3[tid], be3 = bn3[9 + tid], m3 = bn3[18 + tid], v3 = bn3[27 + tid];
        a3[tid] = g3 * rsqrtf(v3 + 1e-5f);
        ws[WS_B3 + tid] = be3 - m3 * a3[tid];
        float g4 = bn4[tid], be4 = bn4[9 + tid], m4 = bn4[18 + tid], v4 = bn4[27 + tid];
        a4[tid] = g4 * rsqrtf(v4 + 1e-5f);
        ws[WS_B4 + tid] = be4 - m4 * a4[tid];
    }
    __syncthreads();

    for (int e = tid; e < CD1 * CHANS; e += blockDim.x) {
        int o = e / CHANS, c = e - o * CHANS;
        float m = 0.0f;
        for (int h = 0; h < DEPTH; ++h) m += t1w[o * DEPTH + h] * cw[h * CHANS + c];
        ws[WS_W2 + e] = a2[o] * a1[o] * m;
    }
    for (int e = tid; e < CD2 * CD1; e += blockDim.x) {
        int o = e / CD1;
        ws[WS_CC1 + e] = a3[o] * cc1w[e] * 22.0f;
    }
    for (int e = tid; e < CD2 * CHANS; e += blockDim.x) {
        int f = e / CHANS;
        ws[WS_CC2 + e] = a4[f] * cc2w[e];
    }
    for (int e = tid; e < 45; e += blockDim.x) {
        int l = e / 9, o = e - l * 9;
        ws[WS_BL + e] = cbB[(l * 3 + 0) * 9 + o] + cbB[(l * 3 + 1) * 9 + o] + cbB[(l * 3 + 2) * 9 + o];
    }
    // adjacency: relu(A*sigmoid(mask)), zero diag, symmetrize, normalized Laplacian
    for (int e = tid; e < 484; e += blockDim.x) {
        int c = e / 22, d = e - c * 22;
        float v = A[e] / (1.0f + expf(-Am[e]));
        v = fmaxf(v, 0.0f);
        if (c == d) v = 0.0f;
        Ap[e] = v;
    }
    __syncthreads();
    for (int e = tid; e < 484; e += blockDim.x) {
        int c = e / 22, d = e - c * 22;
        As[e] = Ap[e] + Ap[d * 22 + c];
    }
    __syncthreads();
    if (tid < 22) {
        float s = 0.0f;
        for (int d = 0; d < 22; ++d) s += As[tid * 22 + d];
        dis[tid] = rsqrtf(s + 1e-10f);
    }
    __syncthreads();
    for (int e = tid; e < 484; e += blockDim.x) {
        int c = e / 22, d = e - c * 22;
        // 2*L/lmax - I with lmax=2 reduces to -dis[c]*As*dis[d]
        float v = -dis[c] * As[e] * dis[d];
        L1s[e] = v;
        ws[WS_L1 + e] = v;
    }
    __syncthreads();
    for (int e = tid; e < 484; e += blockDim.x) {
        int c = e / 22, d = e - c * 22;
        float s = 0.0f;
        for (int k2 = 0; k2 < 22; ++k2) s += L1s[c * 22 + k2] * L1s[k2 * 22 + d];
        ws[WS_L2 + e] = 2.0f * s - (c == d ? 1.0f : 0.0f);
    }
}

// LDS layout (floats), wl-dim padded to 17 to break bank-conflict strides
#define OXS  0              // 22 x 92 input slice
#define OG   2048           // 24 x 22 x 17 gelu(bn2(conv)) tile
#define OS   11024          // 24 x 17 softmax weights
#define OX   11456          // 9 x 22 x 17 cheby state (also xp temp 24*16)
#define OY1  2048           // 9 x 22 x 17 (reuses OG after phase 4)
#define OY2  (2048 + 3366)
#define SMEM_F 14848

__global__ __launch_bounds__(256) void main_kernel(
    const float* __restrict__ x, const float* __restrict__ t2w,
    const float* __restrict__ daw_g, const float* __restrict__ dab_g,
    const float* __restrict__ cbW, float* __restrict__ ws)
{
    __shared__ float sm[SMEM_F];
    const int tid = threadIdx.x;
    const int b = blockIdx.y;
    const int w0 = blockIdx.x * TW;
    const float* cst = ws;
    float* zbuf = ws + WS_Z;

    // Phase 1: stage x[b, c, w0 .. w0+89] into LDS (row pad 92 for float4 align)
    for (int e = tid; e < 22 * 92; e += 256) {
        int c = e / 92, j = e - c * 92;
        int s = w0 + j;
        float v = 0.0f;
        if (j < 90 && s < SAMPLES) v = x[(b * CHANS + c) * SAMPLES + s];
        sm[OXS + e] = v;
    }
    __syncthreads();

    // Phase 2: depthwise conv (fused stage1/2/bn1/bn2) + gelu -> g[o][c][wl]
    for (int pair = tid; pair < CD1 * CHANS; pair += 256) {
        int o = pair / CHANS, c = pair - o * CHANS;
        float acc[TW];
        #pragma unroll
        for (int t = 0; t < TW; ++t) acc[t] = 0.0f;
        const float* Kg = t2w + o * KT;
        const int xbase = OXS + c * 92;
        #pragma unroll
        for (int k = 0; k < KT; ++k) {
            float kw = Kg[k];
            #pragma unroll
            for (int t = 0; t < TW; ++t)
                acc[t] = fmaf(kw, sm[xbase + k + t], acc[t]);
        }
        float w2 = cst[WS_W2 + pair];
        float dd = cst[WS_D + o];
        float* gp = &sm[OG + (o * CHANS + c) * 17];
        #pragma unroll
        for (int t = 0; t < TW; ++t) {
            float v = fmaf(w2, acc[t], dd);
            gp[t] = gelu_exact(v);
        }
    }
    __syncthreads();

    // Phase 3: depth attention. xp = mean over c; (7,1) conv over depth; softmax
    for (int e = tid; e < CD1 * TW; e += 256) {
        int d = e >> 4, wl = e & 15;
        float s = 0.0f;
        #pragma unroll
        for (int c = 0; c < CHANS; ++c) s += sm[OG + (d * CHANS + c) * 17 + wl];
        sm[OX + e] = s * (1.0f / 22.0f);   // xp temp in OX region
    }
    __syncthreads();
    {
        float dabv = dab_g[0];
        for (int e = tid; e < CD1 * TW; e += 256) {
            int d = e >> 4, wl = e & 15;
            float y = dabv;
            #pragma unroll
            for (int j = 0; j < 7; ++j) {
                int dd = d + j - 3;
                if (dd >= 0 && dd < CD1) y += daw_g[j] * sm[OX + dd * TW + wl];
            }
            sm[OS + d * 17 + wl] = y;
        }
    }
    __syncthreads();
    if (tid < TW) {
        int wl = tid;
        float mx = -1e30f;
        for (int d = 0; d < CD1; ++d) mx = fmaxf(mx, sm[OS + d * 17 + wl]);
        float sum = 0.0f;
        for (int d = 0; d < CD1; ++d) {
            float e2 = expf(sm[OS + d * 17 + wl] - mx);
            sm[OS + d * 17 + wl] = e2;
            sum += e2;
        }
        float inv = 1.0f / sum;
        for (int d = 0; d < CD1; ++d) sm[OS + d * 17 + wl] *= inv;
    }
    __syncthreads();

    // Phase 4: cconv1 (folded bn3, x22) -> X[f][c][wl]
    for (int pair = tid; pair < CD2 * CHANS; pair += 256) {
        int o = pair / CHANS, c = pair - o * CHANS;
        float acc[TW];
        float bb = cst[WS_B3 + o];
        #pragma unroll
        for (int t = 0; t < TW; ++t) acc[t] = bb;
        for (int i = 0; i < CD1; ++i) {
            float cf = cst[WS_CC1 + o * CD1 + i];
            #pragma unroll
            for (int t = 0; t < TW; ++t)
                acc[t] = fmaf(cf * sm[OS + i * 17 + t], sm[OG + (i * CHANS + c) * 17 + t], acc[t]);
        }
        float* xp = &sm[OX + (o * CHANS + c) * 17];
        #pragma unroll
        for (int t = 0; t < TW; ++t) xp[t] = acc[t];
    }
    __syncthreads();

    // Phase 5: 5 Chebyshev GCN layers. Y1 = X*T1^T, Y2 = X*T2^T, contract with W
    for (int l = 0; l < 5; ++l) {
        for (int j = tid; j < 288; j += 256) {
            int m = (j >= 144) ? 1 : 0;
            int fj = j - m * 144;
            int f = fj >> 4, wl = fj & 15;
            const float* Lg = cst + (m ? WS_L2 : WS_L1);
            float xr[CHANS];
            #pragma unroll
            for (int d = 0; d < CHANS; ++d) xr[d] = sm[OX + (f * CHANS + d) * 17 + wl];
            float* yo = &sm[(m ? OY2 : OY1) + f * CHANS * 17 + wl];
            for (int c = 0; c < CHANS; ++c) {
                float a = 0.0f;
                #pragma unroll
                for (int d = 0; d < CHANS; ++d) a = fmaf(Lg[c * 22 + d], xr[d], a);
                yo[c * 17] = a;
            }
        }
        __syncthreads();
        float accA[2][CD2];
        int nj = 0;
        for (int j = tid; j < 352; j += 256, ++nj) {
            int c = j >> 4, wl = j & 15;
            #pragma unroll
            for (int o = 0; o < CD2; ++o) accA[nj][o] = cst[WS_BL + l * 9 + o];
            #pragma unroll
            for (int f = 0; f < CD2; ++f) {
                float xv = sm[OX  + (f * CHANS + c) * 17 + wl];
                float y1 = sm[OY1 + (f * CHANS + c) * 17 + wl];
                float y2 = sm[OY2 + (f * CHANS + c) * 17 + wl];
                const float* w0p = cbW + ((l * 3 + 0) * 9 + f) * 9;
                const float* w1p = cbW + ((l * 3 + 1) * 9 + f) * 9;
                const float* w2p = cbW + ((l * 3 + 2) * 9 + f) * 9;
                #pragma unroll
                for (int o = 0; o < CD2; ++o)
                    accA[nj][o] = fmaf(w0p[o], xv, fmaf(w1p[o], y1, fmaf(w2p[o], y2, accA[nj][o])));
            }
        }
        __syncthreads();
        nj = 0;
        for (int j = tid; j < 352; j += 256, ++nj) {
            int c = j >> 4, wl = j & 15;
            #pragma unroll
            for (int o = 0; o < CD2; ++o)
                sm[OX + (o * CHANS + c) * 17 + wl] = fmaxf(accA[nj][o], 0.0f);
        }
        __syncthreads();
    }

    // Phase 6: depthwise channel conv (folded bn4) + gelu -> zbuf
    for (int j = tid; j < CD2 * TW; j += 256) {
        int f = j >> 4, wl = j & 15;
        float a = cst[WS_B4 + f];
        #pragma unroll
        for (int c = 0; c < CHANS; ++c)
            a = fmaf(cst[WS_CC2 + f * CHANS + c], sm[OX + (f * CHANS + c) * 17 + wl], a);
        float z = gelu_exact(a);
        int w = w0 + wl;
        if (w < W1) zbuf[(b * CD2 + f) * W1 + w] = z;
    }
}

__global__ __launch_bounds__(256) void head_kernel(
    const float* __restrict__ ws, const float* __restrict__ fc1w,
    const float* __restrict__ fc1b, const float* __restrict__ w1,
    const float* __restrict__ b1, const float* __restrict__ w2,
    const float* __restrict__ b2, float* __restrict__ out)
{
    __shared__ float red[5][256];
    __shared__ float l5[5];
    __shared__ float hbuf[64];
    const int tid = threadIdx.x;
    const int b = blockIdx.x;
    const float* zb = ws + WS_Z + b * CD2 * W1;

    float part[5] = {0, 0, 0, 0, 0};
    for (int i = tid; i < FEAT; i += 256) {
        int f = i / WP, t = i - f * WP;
        const float* zp = zb + f * W1 + 5 * t;
        float pooled = 0.2f * (zp[0] + zp[1] + zp[2] + zp[3] + zp[4]);
        #pragma unroll
        for (int j = 0; j < 5; ++j) part[j] = fmaf(pooled, fc1w[i * 5 + j], part[j]);
    }
    #pragma unroll
    for (int j = 0; j < 5; ++j) red[j][tid] = part[j];
    __syncthreads();
    for (int ofs = 128; ofs > 0; ofs >>= 1) {
        if (tid < ofs) {
            #pragma unroll
            for (int j = 0; j < 5; ++j) red[j][tid] += red[j][tid + ofs];
        }
        __syncthreads();
    }
    if (tid < 5) l5[tid] = red[tid][0] + fc1b[tid];
    __syncthreads();
    if (tid < 64) {
        float a = b1[tid];
        #pragma unroll
        for (int j = 0; j < 5; ++j) a = fmaf(l5[j], w1[j * 64 + tid], a);
        hbuf[tid] = (a > 0.0f) ? a : expm1f(a);
    }
    __syncthreads();
    if (tid == 0) {
        float o4[4];
        #pragma unroll
        for (int m = 0; m < 4; ++m) {
            float a = b2[m];
            for (int k = 0; k < 64; ++k) a = fmaf(hbuf[k], w2[k * 4 + m], a);
            o4[m] = a;
        }
        float mx = fmaxf(fmaxf(o4[0], o4[1]), fmaxf(o4[2], o4[3]));
        float s = 0.0f;
        #pragma unroll
        for (int m = 0; m < 4; ++m) { o4[m] = expf(o4[m] - mx); s += o4[m]; }
        float inv = 1.0f / s;
        #pragma unroll
        for (int m = 0; m < 4; ++m) out[b * 4 + m] = o4[m] * inv;
    }
}

extern "C" void kernel_launch(void* const* d_in, const int* in_sizes, int n_in,
                              void* d_out, int out_size, void* d_ws, size_t ws_size,
                              hipStream_t stream)
{
    const float* x    = (const float*)d_in[0];
    const float* cw   = (const float*)d_in[1];
    const float* t1w  = (const float*)d_in[2];
    const float* bn1  = (const float*)d_in[3];
    const float* t2w  = (const float*)d_in[4];
    const float* bn2  = (const float*)d_in[5];
    const float* daw  = (const float*)d_in[6];
    const float* dab  = (const float*)d_in[7];
    const float* cc1w = (const float*)d_in[8];
    const float* bn3  = (const float*)d_in[9];
    const float* A    = (const float*)d_in[10];
    const float* Am   = (const float*)d_in[11];
    const float* cbW  = (const float*)d_in[12];
    const float* cbB  = (const float*)d_in[13];
    const float* cc2w = (const float*)d_in[14];
    const float* bn4  = (const float*)d_in[15];
    const float* fc1w = (const float*)d_in[16];
    const float* fc1b = (const float*)d_in[17];
    const float* w1   = (const float*)d_in[18];
    const float* b1   = (const float*)d_in[19];
    const float* w2   = (const float*)d_in[20];
    const float* b2   = (const float*)d_in[21];
    float* ws  = (float*)d_ws;
    float* out = (float*)d_out;

    hipLaunchKernelGGL(precompute_kernel, dim3(1), dim3(256), 0, stream,
                       cw, t1w, bn1, t2w, bn2, cc1w, bn3, A, Am, cbB, cc2w, bn4, ws);
    hipLaunchKernelGGL(main_kernel, dim3(NT, B_), dim3(256), 0, stream,
                       x, t2w, daw, dab, cbW, ws);
    hipLaunchKernelGGL(head_kernel, dim3(B_), dim3(256), 0, stream,
                       ws, fc1w, fc1b, w1, b1, w2, b2, out);
}